// Round 6
// baseline (453.389 us; speedup 1.0000x reference)
//
#include <hip/hip_runtime.h>
#include <math.h>

#define E 128
#define NH 4
#define HD 32
#define LN_EPS 1e-5f
#define CHN 128          // tokens per chunk
#define NBLK 256         // blocks (1 per CU, all co-resident)
#define PW 129           // padded LDS row stride

#define BAR_LGKM()    do { asm volatile("s_waitcnt lgkmcnt(0)" ::: "memory"); __builtin_amdgcn_s_barrier(); } while (0)
#define BAR_VM_LGKM() do { asm volatile("s_waitcnt vmcnt(0) lgkmcnt(0)" ::: "memory"); __builtin_amdgcn_s_barrier(); } while (0)

typedef const __attribute__((address_space(1))) void* gas_p;
typedef __attribute__((address_space(3))) void* las_p;
__device__ __forceinline__ void gload_lds16(const float* g, void* l) {
    __builtin_amdgcn_global_load_lds((gas_p)(const void*)g, (las_p)l, 16, 0, 0);
}

typedef float f32x4 __attribute__((ext_vector_type(4)));

// ---------------- K0: per-batch query precompute (parallel, coalesced) ----------------
__global__ __launch_bounds__(512)
void k0_prep(const int* __restrict__ didx,
             const float* __restrict__ emb,
             const float* __restrict__ qpw, const float* __restrict__ qpb,
             const float* __restrict__ wq, const float* __restrict__ bq,
             const float* __restrict__ wk,
             float* __restrict__ u_s, int B)
{
    __shared__ float wbuf[E * PW];
    __shared__ float de_sh[4][E];
    __shared__ float q_sh[4][E];
    __shared__ float qh_sh[4][E];
    __shared__ int didx_sh[8];
    const int t = threadIdx.x;       // 512
    const int bb = t >> 7, c = t & 127;
    const float scale = 0.17677669529663687f; // 1/sqrt(32)
    if (t < B) didx_sh[t] = didx[t];
    __syncthreads();
    for (int b0 = 0; b0 < B; b0 += 4) {
        const int b = b0 + bb;
        const bool act = b < B;
        if (act) de_sh[bb][c] = emb[(long)didx_sh[b] * E + c];
        for (int i = t; i < E * E; i += 512) wbuf[(i >> 7) * PW + (i & 127)] = qpw[i];
        __syncthreads();
        if (act) {
            float a = qpb[c];
            for (int j = 0; j < E; ++j) a += wbuf[c * PW + j] * de_sh[bb][j];
            q_sh[bb][c] = a;
        }
        __syncthreads();
        for (int i = t; i < E * E; i += 512) wbuf[(i >> 7) * PW + (i & 127)] = wq[i];
        __syncthreads();
        if (act) {
            float a = bq[c];
            for (int j = 0; j < E; ++j) a += wbuf[c * PW + j] * q_sh[bb][j];
            qh_sh[bb][c] = a;
        }
        __syncthreads();
        for (int i = t; i < E * E; i += 512) wbuf[(i >> 7) * PW + (i & 127)] = wk[i];
        __syncthreads();
        if (act) {
            #pragma unroll
            for (int h = 0; h < NH; ++h) {
                float a = 0.f;
                for (int d = 0; d < HD; ++d)
                    a += qh_sh[bb][h * HD + d] * wbuf[(h * HD + d) * PW + c];
                u_s[((long)b * NH + h) * E + c] = a * scale;
            }
        }
        __syncthreads();
    }
}

// ---------------- MEGA: per-batch {P1 attention-partials; gridsync; P2 ln; P3 residual} ----------------
__global__ __launch_bounds__(512, 2)
void mega(const float* __restrict__ x, const float* __restrict__ u_s,
          const float* __restrict__ wvw, const float* __restrict__ bv,
          const float* __restrict__ wo, const float* __restrict__ bo,
          const float* __restrict__ lng, const float* __restrict__ lnb,
          float* __restrict__ out,
          float* __restrict__ ctx_num, float* __restrict__ Lsum,
          int* __restrict__ cnt,
          int N, int B, int nk)
{
    __shared__ float4 tile[2][4096];                 // 128 KB double buffer
    __shared__ __align__(16) float p_sh[NH][CHN];    // 2 KB
    __shared__ __align__(16) float red_sh[8][32][20];// 20 KB (stride 20, conflict-free)
    __shared__ float lacc[8][NH];
    __shared__ float invl_sh[NH];
    __shared__ __align__(16) float sctx_sh[512];
    __shared__ float partred[4][128];
    __shared__ float vec1_sh[128];
    __shared__ float lnv_sh[128];
    __shared__ float red512[512];

    const int t = threadIdx.x;            // 512
    const int lane = t & 63;
    const int wvid = t >> 6;              // wave 0..7
    const int g = blockIdx.x;             // 0..255

    const int q    = t & 31;
    const int cseg = t >> 5;              // 0..15
    const int q2   = t >> 4;
    const int th   = t & 15;
    const int n2   = (q2 << 2) | (th >> 2);
    const int h2   = th & 3;

    auto STAGE = [&](int bb, int kk, int buf) {
        const float* xb = x + (long)bb * E * N + (long)(g * nk + kk) * CHN;
        float4* tb = &tile[buf][0];
        #pragma unroll
        for (int r = 0; r < 8; ++r) {
            const int sbase = ((r << 3) + wvid) << 6;   // wave-uniform quad base
            const int s = sbase + lane;
            const int c = s >> 5, qg = s & 31;
            gload_lds16(xb + (long)c * N + (qg << 2), (void*)&tb[sbase]);
        }
    };

    int epoch = 0;
    STAGE(0, 0, 0);

    for (int b = 0; b < B; ++b) {
        // ---- per-batch init ----
        float u_reg[8][NH];
        #pragma unroll
        for (int j = 0; j < 8; ++j)
            #pragma unroll
            for (int hh = 0; hh < NH; ++hh)
                u_reg[j][hh] = u_s[((long)b * NH + hh) * E + (cseg << 3) + j];

        float l_loc = 0.f;
        float acc[NH][8];
        #pragma unroll
        for (int hh = 0; hh < NH; ++hh)
            #pragma unroll
            for (int j = 0; j < 8; ++j) acc[hh][j] = 0.f;

        BAR_VM_LGKM();      // chunk 0 of this batch staged
        int cur = 0;

        // ---- P1: fused scores + softmax(no-shift) + ctx over nk chunks ----
        for (int k = 0; k < nk; ++k) {
            if (k + 1 < nk) STAGE(b, k + 1, cur ^ 1);
            const float4* lt = &tile[cur][0];

            float4 xc[8];
            float sa[4][NH];
            #pragma unroll
            for (int tok = 0; tok < 4; ++tok)
                #pragma unroll
                for (int hh = 0; hh < NH; ++hh) sa[tok][hh] = 0.f;
            #pragma unroll
            for (int j = 0; j < 8; ++j) {
                float4 xq = lt[(((cseg << 3) + j) << 5) + q];
                xc[j] = xq;
                #pragma unroll
                for (int hh = 0; hh < NH; ++hh) {
                    const float uv = u_reg[j][hh];
                    sa[0][hh] = fmaf(uv, xq.x, sa[0][hh]);
                    sa[1][hh] = fmaf(uv, xq.y, sa[1][hh]);
                    sa[2][hh] = fmaf(uv, xq.z, sa[2][hh]);
                    sa[3][hh] = fmaf(uv, xq.w, sa[3][hh]);
                }
            }
            #pragma unroll
            for (int tok = 0; tok < 4; ++tok)
                #pragma unroll
                for (int hh = 0; hh < NH; ++hh)
                    sa[tok][hh] += __shfl_xor(sa[tok][hh], 32);
            if (lane < 32) {
                *(float4*)&red_sh[wvid][q][0]  = make_float4(sa[0][0], sa[0][1], sa[0][2], sa[0][3]);
                *(float4*)&red_sh[wvid][q][4]  = make_float4(sa[1][0], sa[1][1], sa[1][2], sa[1][3]);
                *(float4*)&red_sh[wvid][q][8]  = make_float4(sa[2][0], sa[2][1], sa[2][2], sa[2][3]);
                *(float4*)&red_sh[wvid][q][12] = make_float4(sa[3][0], sa[3][1], sa[3][2], sa[3][3]);
            }
            BAR_LGKM();

            float s = red_sh[0][q2][th] + red_sh[1][q2][th]
                    + red_sh[2][q2][th] + red_sh[3][q2][th]
                    + red_sh[4][q2][th] + red_sh[5][q2][th]
                    + red_sh[6][q2][th] + red_sh[7][q2][th];
            float p = __expf(s);
            l_loc += p;
            p_sh[h2][n2] = p;
            BAR_LGKM();

            float4 pq[NH];
            #pragma unroll
            for (int hh = 0; hh < NH; ++hh) pq[hh] = *(const float4*)&p_sh[hh][q << 2];
            #pragma unroll
            for (int j = 0; j < 8; ++j) {
                const float4 xq = xc[j];
                #pragma unroll
                for (int hh = 0; hh < NH; ++hh) {
                    float a = acc[hh][j];
                    a = fmaf(pq[hh].x, xq.x, a); a = fmaf(pq[hh].y, xq.y, a);
                    a = fmaf(pq[hh].z, xq.z, a); a = fmaf(pq[hh].w, xq.w, a);
                    acc[hh][j] = a;
                }
            }
            BAR_VM_LGKM();
            cur ^= 1;
        }

        // ---- P1 epilogue: fold + device atomics into tiny accumulators ----
        #pragma unroll
        for (int hh = 0; hh < NH; ++hh) {
            #pragma unroll
            for (int j = 0; j < 8; ++j) {
                float v = acc[hh][j];
                #pragma unroll
                for (int o = 16; o > 0; o >>= 1) v += __shfl_xor(v, o);
                if (q == 0)
                    atomicAdd(&ctx_num[((long)b * NH + hh) * E + (cseg << 3) + j], v);
            }
        }
        float r = l_loc;
        r += __shfl_xor(r, 4); r += __shfl_xor(r, 8);
        r += __shfl_xor(r, 16); r += __shfl_xor(r, 32);
        if (lane < 4) lacc[wvid][lane] = r;
        __syncthreads();
        if (t < NH) {
            float L = 0.f;
            #pragma unroll
            for (int w = 0; w < 8; ++w) L += lacc[w][t];
            atomicAdd(&Lsum[b * NH + t], L);
        }

        // ---- grid sync ----
        __syncthreads();
        if (t == 0) {
            __threadfence();
            __hip_atomic_fetch_add(cnt, 1, __ATOMIC_ACQ_REL, __HIP_MEMORY_SCOPE_AGENT);
            const int target = NBLK * (epoch + 1);
            while (__hip_atomic_load(cnt, __ATOMIC_ACQUIRE, __HIP_MEMORY_SCOPE_AGENT) < target)
                __builtin_amdgcn_s_sleep(2);
            __threadfence();
        }
        __syncthreads();
        ++epoch;

        // ---- P2: every block redundantly computes ln_b (2KB reads, weights L2-hot) ----
        if (t < NH)
            invl_sh[t] = 1.f / __hip_atomic_load(&Lsum[b * NH + t], __ATOMIC_RELAXED,
                                                 __HIP_MEMORY_SCOPE_AGENT);
        __syncthreads();
        sctx_sh[t] = __hip_atomic_load(&ctx_num[(long)b * NH * E + t], __ATOMIC_RELAXED,
                                       __HIP_MEMORY_SCOPE_AGENT) * invl_sh[t >> 7];
        __syncthreads();
        {
            const int rr = t & 127, qt = t >> 7;
            const int hR = rr >> 5;
            float pa = 0.f;
            const float* wrow = wvw + rr * E + qt * 32;
            const float* srow = &sctx_sh[hR * 128 + qt * 32];
            #pragma unroll
            for (int c2 = 0; c2 < 32; ++c2) pa = fmaf(wrow[c2], srow[c2], pa);
            partred[qt][rr] = pa;
            __syncthreads();
            if (t < 128)
                vec1_sh[t] = bv[t] + partred[0][t] + partred[1][t] + partred[2][t] + partred[3][t];
            __syncthreads();
            float po = 0.f;
            const float* worow = wo + rr * E + qt * 32;
            #pragma unroll
            for (int c2 = 0; c2 < 32; ++c2) po = fmaf(worow[c2], vec1_sh[qt * 32 + c2], po);
            partred[qt][rr] = po;
            __syncthreads();
            float ov = 0.f;
            if (t < 128) ov = bo[t] + partred[0][t] + partred[1][t] + partred[2][t] + partred[3][t];
            red512[t] = (t < 128) ? ov : 0.f;
            __syncthreads();
            for (int st = 64; st > 0; st >>= 1) { if (t < st) red512[t] += red512[t + st]; __syncthreads(); }
            const float mu = red512[0] * (1.f / E);
            __syncthreads();
            const float d = (t < 128) ? (ov - mu) : 0.f;
            red512[t] = d * d;
            __syncthreads();
            for (int st = 64; st > 0; st >>= 1) { if (t < st) red512[t] += red512[t + st]; __syncthreads(); }
            const float var = red512[0] * (1.f / E);
            if (t < 128) lnv_sh[t] = d * rsqrtf(var + LN_EPS) * lng[t] + lnb[t];
            __syncthreads();
        }

        // ---- prefetch next batch chunk 0 (hides under P3 streaming) ----
        if (b + 1 < B) STAGE(b + 1, 0, 0);

        // ---- P3: out_b = x_b + ln_b (x_b L3-hot from P1; nt stores) ----
        {
            const float lnv = lnv_sh[g >> 1];   // block covers half of row c = g>>1
            const long base4 = ((long)b * E * N + (long)(g >> 1) * N + (long)(g & 1) * (N >> 1)) >> 2;
            const f32x4* x4 = (const f32x4*)x;
            f32x4* o4 = (f32x4*)out;
            const int seg4 = (N >> 1) >> 2;     // 16384 float4 per block
            for (int i = t; i < seg4; i += 512) {
                f32x4 v = x4[base4 + i];
                v += lnv;
                __builtin_nontemporal_store(v, o4 + base4 + i);
            }
        }
        // loop-top BAR_VM_LGKM waits the chunk-0 prefetch
    }
}

extern "C" void kernel_launch(void* const* d_in, const int* in_sizes, int n_in,
                              void* d_out, int out_size, void* d_ws, size_t ws_size,
                              hipStream_t stream) {
    const float* x   = (const float*)d_in[0];
    const int*   didx= (const int*)d_in[1];
    const float* emb = (const float*)d_in[2];
    const float* qpw = (const float*)d_in[3];
    const float* qpb = (const float*)d_in[4];
    const float* wq  = (const float*)d_in[5];
    const float* bq  = (const float*)d_in[6];
    const float* wk  = (const float*)d_in[7];
    // d_in[8] = bk — cancels in softmax, unused
    const float* wvw = (const float*)d_in[9];
    const float* bv  = (const float*)d_in[10];
    const float* wo  = (const float*)d_in[11];
    const float* bo  = (const float*)d_in[12];
    const float* lng = (const float*)d_in[13];
    const float* lnb = (const float*)d_in[14];
    float* out = (float*)d_out;

    const int B = in_sizes[1];
    const long totalx = (long)in_sizes[0];
    const int N = (int)(totalx / ((long)B * E)); // 131072
    const int nk = N / (CHN * NBLK);             // 4 chunks per block per batch

    // workspace: [cnt][pad][Lsum B*NH][ctx_num B*NH*E][u_s B*NH*E]
    char* wsb = (char*)d_ws;
    int*   cnt     = (int*)wsb;                        // 1 int
    float* Lsum    = (float*)(wsb + 128);              // B*NH
    float* ctx_num = (float*)(wsb + 1024);             // B*NH*E
    float* u_s     = (float*)(wsb + 1024 + (long)B * NH * E * 4);

    hipMemsetAsync(d_ws, 0, 1024 + (long)B * NH * E * 4, stream);

    k0_prep<<<1, 512, 0, stream>>>(didx, emb, qpw, qpb, wq, bq, wk, u_s, B);

    mega<<<NBLK, 512, 0, stream>>>(x, u_s, wvw, bv, wo, bo, lng, lnb, out,
                                   ctx_num, Lsum, cnt, N, B, nk);
}

// Round 8
// 427.142 us; speedup vs baseline: 1.0614x; 1.0614x over previous
//
#include <hip/hip_runtime.h>
#include <math.h>

#define E 128
#define NH 4
#define HD 32
#define LN_EPS 1e-5f
#define CHN 128          // tokens per chunk
#define NBLK 256         // kA blocks (1 per CU)
#define PW 129           // padded LDS row stride

#define BAR_LGKM()    do { asm volatile("s_waitcnt lgkmcnt(0)" ::: "memory"); __builtin_amdgcn_s_barrier(); } while (0)
#define BAR_VM_LGKM() do { asm volatile("s_waitcnt vmcnt(0) lgkmcnt(0)" ::: "memory"); __builtin_amdgcn_s_barrier(); } while (0)

typedef const __attribute__((address_space(1))) void* gas_p;
typedef __attribute__((address_space(3))) void* las_p;
__device__ __forceinline__ void gload_lds16(const float* g, void* l) {
    __builtin_amdgcn_global_load_lds((gas_p)(const void*)g, (las_p)l, 16, 0, 0);
}

typedef float f32x4 __attribute__((ext_vector_type(4)));

// ---------------- K0: per-batch query precompute (parallel, coalesced) ----------------
__global__ __launch_bounds__(512)
void k0_prep(const int* __restrict__ didx,
             const float* __restrict__ emb,
             const float* __restrict__ qpw, const float* __restrict__ qpb,
             const float* __restrict__ wq, const float* __restrict__ bq,
             const float* __restrict__ wk,
             float* __restrict__ u_s, int B)
{
    __shared__ float wbuf[E * PW];
    __shared__ float de_sh[4][E];
    __shared__ float q_sh[4][E];
    __shared__ float qh_sh[4][E];
    __shared__ int didx_sh[8];
    const int t = threadIdx.x;       // 512
    const int bb = t >> 7, c = t & 127;
    const float scale = 0.17677669529663687f; // 1/sqrt(32)
    if (t < B) didx_sh[t] = didx[t];
    __syncthreads();
    for (int b0 = 0; b0 < B; b0 += 4) {
        const int b = b0 + bb;
        const bool act = b < B;
        if (act) de_sh[bb][c] = emb[(long)didx_sh[b] * E + c];
        for (int i = t; i < E * E; i += 512) wbuf[(i >> 7) * PW + (i & 127)] = qpw[i];
        __syncthreads();
        if (act) {
            float a = qpb[c];
            for (int j = 0; j < E; ++j) a += wbuf[c * PW + j] * de_sh[bb][j];
            q_sh[bb][c] = a;
        }
        __syncthreads();
        for (int i = t; i < E * E; i += 512) wbuf[(i >> 7) * PW + (i & 127)] = wq[i];
        __syncthreads();
        if (act) {
            float a = bq[c];
            for (int j = 0; j < E; ++j) a += wbuf[c * PW + j] * q_sh[bb][j];
            qh_sh[bb][c] = a;
        }
        __syncthreads();
        for (int i = t; i < E * E; i += 512) wbuf[(i >> 7) * PW + (i & 127)] = wk[i];
        __syncthreads();
        if (act) {
            #pragma unroll
            for (int h = 0; h < NH; ++h) {
                float a = 0.f;
                for (int d = 0; d < HD; ++d)
                    a += qh_sh[bb][h * HD + d] * wbuf[(h * HD + d) * PW + c];
                u_s[((long)b * NH + h) * E + c] = a * scale;
            }
        }
        __syncthreads();
    }
}

// ---------------- KA: one batch. fused scores+softmax+ctx; last block does V/O-proj + LN ----------------
__global__ __launch_bounds__(512, 2)
void kA_attn(const float* __restrict__ x, const float* __restrict__ u_s,
             const float* __restrict__ wvw, const float* __restrict__ bv,
             const float* __restrict__ wo, const float* __restrict__ bo,
             const float* __restrict__ lng, const float* __restrict__ lnb,
             float* __restrict__ ctx_num, float* __restrict__ Lsum,
             int* __restrict__ done_cnt, float* __restrict__ ln_o,
             int N, int b, int nk)
{
    __shared__ float4 tile[2][4096];                 // 128 KB double buffer (reused as wbuf in P2)
    __shared__ __align__(16) float p_sh[NH][CHN];    // 2 KB
    __shared__ __align__(16) float red_sh[8][32][20];// 20 KB (stride 20, conflict-free)
    __shared__ float lacc[8][NH];
    __shared__ float invl_sh[NH];
    __shared__ __align__(16) float sctx_sh[512];
    __shared__ float partred[4][128];
    __shared__ float vec1_sh[128];
    __shared__ float red512[512];
    __shared__ int isLast;

    const int t = threadIdx.x;            // 512
    const int lane = t & 63;
    const int wvid = t >> 6;              // wave 0..7
    const int bi = blockIdx.x;            // 0..255

    const int q    = t & 31;
    const int cseg = t >> 5;              // 0..15
    const int q2   = t >> 4;
    const int th   = t & 15;
    const int n2   = (q2 << 2) | (th >> 2);
    const int h2   = th & 3;

    auto STAGE = [&](int kk, int buf) {
        const float* xb = x + (long)b * E * N + (long)(bi * nk + kk) * CHN;
        float4* tb = &tile[buf][0];
        #pragma unroll
        for (int r = 0; r < 8; ++r) {
            const int sbase = ((r << 3) + wvid) << 6;   // wave-uniform quad base
            const int s = sbase + lane;
            const int c = s >> 5, qg = s & 31;
            gload_lds16(xb + (long)c * N + (qg << 2), (void*)&tb[sbase]);
        }
    };

    // u fragment in registers
    float u_reg[8][NH];
    #pragma unroll
    for (int j = 0; j < 8; ++j)
        #pragma unroll
        for (int hh = 0; hh < NH; ++hh)
            u_reg[j][hh] = u_s[((long)b * NH + hh) * E + (cseg << 3) + j];

    float l_loc = 0.f;
    float acc[NH][8];
    #pragma unroll
    for (int hh = 0; hh < NH; ++hh)
        #pragma unroll
        for (int j = 0; j < 8; ++j) acc[hh][j] = 0.f;

    STAGE(0, 0);
    BAR_VM_LGKM();
    int cur = 0;

    for (int k = 0; k < nk; ++k) {
        if (k + 1 < nk) STAGE(k + 1, cur ^ 1);
        const float4* lt = &tile[cur][0];

        // ---- scores: read tile once, cache in regs ----
        float4 xc[8];
        float sa[4][NH];
        #pragma unroll
        for (int tok = 0; tok < 4; ++tok)
            #pragma unroll
            for (int hh = 0; hh < NH; ++hh) sa[tok][hh] = 0.f;
        #pragma unroll
        for (int j = 0; j < 8; ++j) {
            float4 xq = lt[(((cseg << 3) + j) << 5) + q];
            xc[j] = xq;
            #pragma unroll
            for (int hh = 0; hh < NH; ++hh) {
                const float uv = u_reg[j][hh];
                sa[0][hh] = fmaf(uv, xq.x, sa[0][hh]);
                sa[1][hh] = fmaf(uv, xq.y, sa[1][hh]);
                sa[2][hh] = fmaf(uv, xq.z, sa[2][hh]);
                sa[3][hh] = fmaf(uv, xq.w, sa[3][hh]);
            }
        }
        #pragma unroll
        for (int tok = 0; tok < 4; ++tok)
            #pragma unroll
            for (int hh = 0; hh < NH; ++hh)
                sa[tok][hh] += __shfl_xor(sa[tok][hh], 32);
        if (lane < 32) {
            *(float4*)&red_sh[wvid][q][0]  = make_float4(sa[0][0], sa[0][1], sa[0][2], sa[0][3]);
            *(float4*)&red_sh[wvid][q][4]  = make_float4(sa[1][0], sa[1][1], sa[1][2], sa[1][3]);
            *(float4*)&red_sh[wvid][q][8]  = make_float4(sa[2][0], sa[2][1], sa[2][2], sa[2][3]);
            *(float4*)&red_sh[wvid][q][12] = make_float4(sa[3][0], sa[3][1], sa[3][2], sa[3][3]);
        }
        BAR_LGKM();

        // ---- reduce -> s; p = exp(s) (no max-shift: |s| << 1) ----
        float s = red_sh[0][q2][th] + red_sh[1][q2][th]
                + red_sh[2][q2][th] + red_sh[3][q2][th]
                + red_sh[4][q2][th] + red_sh[5][q2][th]
                + red_sh[6][q2][th] + red_sh[7][q2][th];
        float p = __expf(s);
        l_loc += p;
        p_sh[h2][n2] = p;
        BAR_LGKM();

        // ---- ctx from cached regs ----
        float4 pq[NH];
        #pragma unroll
        for (int hh = 0; hh < NH; ++hh) pq[hh] = *(const float4*)&p_sh[hh][q << 2];
        #pragma unroll
        for (int j = 0; j < 8; ++j) {
            const float4 xq = xc[j];
            #pragma unroll
            for (int hh = 0; hh < NH; ++hh) {
                float a = acc[hh][j];
                a = fmaf(pq[hh].x, xq.x, a); a = fmaf(pq[hh].y, xq.y, a);
                a = fmaf(pq[hh].z, xq.z, a); a = fmaf(pq[hh].w, xq.w, a);
                acc[hh][j] = a;
            }
        }
        BAR_VM_LGKM();
        cur ^= 1;
    }

    // ---- epilogue: fold + device atomics ----
    #pragma unroll
    for (int hh = 0; hh < NH; ++hh) {
        #pragma unroll
        for (int j = 0; j < 8; ++j) {
            float v = acc[hh][j];
            #pragma unroll
            for (int o = 16; o > 0; o >>= 1) v += __shfl_xor(v, o);
            if (q == 0)
                atomicAdd(&ctx_num[((long)b * NH + hh) * E + (cseg << 3) + j], v);
        }
    }
    float r = l_loc;
    r += __shfl_xor(r, 4); r += __shfl_xor(r, 8);
    r += __shfl_xor(r, 16); r += __shfl_xor(r, 32);
    if (lane < 4) lacc[wvid][lane] = r;
    __syncthreads();
    if (t < NH) {
        float L = 0.f;
        #pragma unroll
        for (int w = 0; w < 8; ++w) L += lacc[w][t];
        atomicAdd(&Lsum[b * NH + t], L);
    }

    // ---- last-finishing block computes ln_b ----
    __syncthreads();
    if (t == 0) {
        __threadfence();
        int v = atomicAdd(&done_cnt[b], 1);
        isLast = (v == NBLK - 1);
    }
    __syncthreads();
    if (!isLast) return;
    __threadfence();

    if (t < NH)
        invl_sh[t] = 1.f / __hip_atomic_load(&Lsum[b * NH + t], __ATOMIC_RELAXED,
                                             __HIP_MEMORY_SCOPE_AGENT);
    __syncthreads();
    sctx_sh[t] = __hip_atomic_load(&ctx_num[(long)b * NH * E + t], __ATOMIC_RELAXED,
                                   __HIP_MEMORY_SCOPE_AGENT) * invl_sh[t >> 7];
    __syncthreads();

    float* wbuf = (float*)&tile[0][0];   // reuse tile LDS (128 KB) for padded weights
    for (int i = t; i < E * E; i += 512) wbuf[(i >> 7) * PW + (i & 127)] = wvw[i];
    __syncthreads();
    {
        const int rr = t & 127, qt = t >> 7;
        const int hR = rr >> 5;
        float pa = 0.f;
        #pragma unroll
        for (int c2 = 0; c2 < 32; ++c2)
            pa = fmaf(wbuf[rr * PW + qt * 32 + c2], sctx_sh[hR * 128 + qt * 32 + c2], pa);
        partred[qt][rr] = pa;
        __syncthreads();
        if (t < 128)
            vec1_sh[t] = bv[t] + partred[0][t] + partred[1][t] + partred[2][t] + partred[3][t];
        __syncthreads();
        for (int i = t; i < E * E; i += 512) wbuf[(i >> 7) * PW + (i & 127)] = wo[i];
        __syncthreads();
        float po = 0.f;
        #pragma unroll
        for (int c2 = 0; c2 < 32; ++c2)
            po = fmaf(wbuf[rr * PW + qt * 32 + c2], vec1_sh[qt * 32 + c2], po);
        partred[qt][rr] = po;
        __syncthreads();
        float ov = 0.f;
        if (t < 128) ov = bo[t] + partred[0][t] + partred[1][t] + partred[2][t] + partred[3][t];
        red512[t] = (t < 128) ? ov : 0.f;
        __syncthreads();
        for (int st = 64; st > 0; st >>= 1) { if (t < st) red512[t] += red512[t + st]; __syncthreads(); }
        const float mu = red512[0] * (1.f / E);
        __syncthreads();
        const float d = (t < 128) ? (ov - mu) : 0.f;
        red512[t] = d * d;
        __syncthreads();
        for (int st = 64; st > 0; st >>= 1) { if (t < st) red512[t] += red512[t + st]; __syncthreads(); }
        const float var = red512[0] * (1.f / E);
        if (t < 128) ln_o[b * E + t] = d * rsqrtf(var + LN_EPS) * lng[t] + lnb[t];
    }
}

// ---------------- KB: out_b = x_b + ln_b (x_b L3-hot from kA_b; nt stores) ----------------
__global__ __launch_bounds__(256)
void kB_resid(const float* __restrict__ x, const float* __restrict__ ln,
              float* __restrict__ out, int sh2, int b, long total4b)
{
    const long base4 = (long)b * total4b;        // per-batch float4 offset (b*E*N/4)
    long i = (long)blockIdx.x * blockDim.x + threadIdx.x;
    const long stride = (long)gridDim.x * blockDim.x;
    const int boff = b * E;
    for (; i < total4b; i += stride) {
        const int c = (int)(i >> sh2);           // row within batch
        const float lnv = ln[boff + c];
        f32x4 v = ((const f32x4*)x)[base4 + i];
        v += lnv;
        __builtin_nontemporal_store(v, ((f32x4*)out) + base4 + i);
    }
}

extern "C" void kernel_launch(void* const* d_in, const int* in_sizes, int n_in,
                              void* d_out, int out_size, void* d_ws, size_t ws_size,
                              hipStream_t stream) {
    const float* x   = (const float*)d_in[0];
    const int*   didx= (const int*)d_in[1];
    const float* emb = (const float*)d_in[2];
    const float* qpw = (const float*)d_in[3];
    const float* qpb = (const float*)d_in[4];
    const float* wq  = (const float*)d_in[5];
    const float* bq  = (const float*)d_in[6];
    const float* wk  = (const float*)d_in[7];
    // d_in[8] = bk — cancels in softmax, unused
    const float* wvw = (const float*)d_in[9];
    const float* bv  = (const float*)d_in[10];
    const float* wo  = (const float*)d_in[11];
    const float* bo  = (const float*)d_in[12];
    const float* lng = (const float*)d_in[13];
    const float* lnb = (const float*)d_in[14];
    float* out = (float*)d_out;

    const int B = in_sizes[1];
    const long totalx = (long)in_sizes[0];
    const int N = (int)(totalx / ((long)B * E)); // 131072
    const int nk = N / (CHN * NBLK);             // 4 chunks per block per batch
    int lgN = 0; while ((1 << lgN) < N) ++lgN;
    const int sh2 = lgN - 2;                     // float4-index -> row shift

    // workspace: [done_cnt B ints][pad][Lsum][ctx_num][ln_o][u_s]
    char* wsb = (char*)d_ws;
    int*   done_cnt = (int*)wsb;                         // B ints
    float* Lsum     = (float*)(wsb + 128);               // B*NH
    float* ctx_num  = (float*)(wsb + 1024);              // B*NH*E
    float* ln_o     = (float*)(wsb + 1024 + (long)B * NH * E * 4);
    float* u_s      = (float*)(wsb + 1024 + (long)B * NH * E * 4 + (long)B * E * 4);

    // zero done_cnt, Lsum, ctx_num
    hipMemsetAsync(d_ws, 0, 1024 + (long)B * NH * E * 4, stream);

    k0_prep<<<1, 512, 0, stream>>>(didx, emb, qpw, qpb, wq, bq, wk, u_s, B);

    const long total4b = (long)E * N / 4;
    for (int b = 0; b < B; ++b) {
        kA_attn<<<NBLK, 512, 0, stream>>>(x, u_s, wvw, bv, wo, bo, lng, lnb,
                                          ctx_num, Lsum, done_cnt, ln_o, N, b, nk);
        kB_resid<<<2048, 256, 0, stream>>>(x, ln_o, out, sh2, b, total4b);
    }
}

// Round 9
// 162.274 us; speedup vs baseline: 2.7940x; 2.6322x over previous
//
#include <hip/hip_runtime.h>
#include <math.h>

#define E 128
#define NH 4
#define HD 32
#define LN_EPS 1e-5f
#define CHN 64           // tokens per chunk
#define BPB 128          // blocks per batch
#define PW 129           // padded LDS row stride

#define BAR_LGKM()    do { asm volatile("s_waitcnt lgkmcnt(0)" ::: "memory"); __builtin_amdgcn_s_barrier(); } while (0)
#define BAR_VM_LGKM() do { asm volatile("s_waitcnt vmcnt(0) lgkmcnt(0)" ::: "memory"); __builtin_amdgcn_s_barrier(); } while (0)

typedef const __attribute__((address_space(1))) void* gas_p;
typedef __attribute__((address_space(3))) void* las_p;
__device__ __forceinline__ void gload_lds16(const float* g, void* l) {
    __builtin_amdgcn_global_load_lds((gas_p)(const void*)g, (las_p)l, 16, 0, 0);
}

typedef float f32x4 __attribute__((ext_vector_type(4)));

// ---------------- K0: per-batch query precompute (parallel, coalesced) ----------------
__global__ __launch_bounds__(512)
void k0_prep(const int* __restrict__ didx,
             const float* __restrict__ emb,
             const float* __restrict__ qpw, const float* __restrict__ qpb,
             const float* __restrict__ wq, const float* __restrict__ bq,
             const float* __restrict__ wk,
             float* __restrict__ u_s, int B)
{
    __shared__ float wbuf[E * PW];
    __shared__ float de_sh[4][E];
    __shared__ float q_sh[4][E];
    __shared__ float qh_sh[4][E];
    __shared__ int didx_sh[8];
    const int t = threadIdx.x;       // 512
    const int bb = t >> 7, c = t & 127;
    const float scale = 0.17677669529663687f; // 1/sqrt(32)
    if (t < B) didx_sh[t] = didx[t];
    __syncthreads();
    for (int b0 = 0; b0 < B; b0 += 4) {
        const int b = b0 + bb;
        const bool act = b < B;
        if (act) de_sh[bb][c] = emb[(long)didx_sh[b] * E + c];
        for (int i = t; i < E * E; i += 512) wbuf[(i >> 7) * PW + (i & 127)] = qpw[i];
        __syncthreads();
        if (act) {
            float a = qpb[c];
            for (int j = 0; j < E; ++j) a += wbuf[c * PW + j] * de_sh[bb][j];
            q_sh[bb][c] = a;
        }
        __syncthreads();
        for (int i = t; i < E * E; i += 512) wbuf[(i >> 7) * PW + (i & 127)] = wq[i];
        __syncthreads();
        if (act) {
            float a = bq[c];
            for (int j = 0; j < E; ++j) a += wbuf[c * PW + j] * q_sh[bb][j];
            qh_sh[bb][c] = a;
        }
        __syncthreads();
        for (int i = t; i < E * E; i += 512) wbuf[(i >> 7) * PW + (i & 127)] = wk[i];
        __syncthreads();
        if (act) {
            #pragma unroll
            for (int h = 0; h < NH; ++h) {
                float a = 0.f;
                for (int d = 0; d < HD; ++d)
                    a += qh_sh[bb][h * HD + d] * wbuf[(h * HD + d) * PW + c];
                u_s[((long)b * NH + h) * E + c] = a * scale;
            }
        }
        __syncthreads();
    }
}

// ---------------- KA: fused scores + softmax(no-shift) + ctx. 256 thr, 2 blocks/CU ----------------
__global__ __launch_bounds__(256, 2)
void kA_attn(const float* __restrict__ x, const float* __restrict__ u_s,
             float* __restrict__ part_ctx, float* __restrict__ part_l,
             int N, int nk)
{
    __shared__ float4 tile[2][2048];                 // 2 x 32 KB double buffer
    __shared__ __align__(16) float p_sh[NH][CHN];    // 1 KB
    __shared__ __align__(16) float red_sh[4][16][20];// 5 KB (stride 20)
    __shared__ float lacc[4][NH];

    const int t = threadIdx.x;            // 256
    const int lane = t & 63;
    const int wvid = t >> 6;              // wave 0..3
    const int g = blockIdx.x;
    const int b = g >> 7;                 // BPB = 128
    const int bi = g & 127;

    const int q    = t & 15;              // token-quad 0..15
    const int cseg = t >> 4;              // row-segment 0..15 (8 rows each)
    // reduce-phase mapping (one (token,head) per thread):
    const int th   = t & 15;              // slot = tok*4 + head
    const int n2   = ((t >> 4) << 2) | (th >> 2);
    const int h2   = th & 3;

    auto STAGE = [&](int kk, int buf) {
        const float* xb = x + (long)b * E * N + (long)(bi * nk + kk) * CHN;
        float4* tb = &tile[buf][0];
        #pragma unroll
        for (int r = 0; r < 8; ++r) {
            const int sbase = ((r << 2) + wvid) << 6;   // wave-uniform quad base
            const int s = sbase + lane;
            const int c = s >> 4, qg = s & 15;
            gload_lds16(xb + (long)c * N + (qg << 2), (void*)&tb[sbase]);
        }
    };

    // u fragment in registers (8 rows per cseg x 4 heads)
    float u_reg[8][NH];
    #pragma unroll
    for (int j = 0; j < 8; ++j)
        #pragma unroll
        for (int hh = 0; hh < NH; ++hh)
            u_reg[j][hh] = u_s[((long)b * NH + hh) * E + (cseg << 3) + j];

    float l_loc = 0.f;
    float acc[NH][8];
    #pragma unroll
    for (int hh = 0; hh < NH; ++hh)
        #pragma unroll
        for (int j = 0; j < 8; ++j) acc[hh][j] = 0.f;

    STAGE(0, 0);
    BAR_VM_LGKM();
    int cur = 0;

    for (int k = 0; k < nk; ++k) {
        if (k + 1 < nk) STAGE(k + 1, cur ^ 1);
        const float4* lt = &tile[cur][0];

        // ---- scores: read tile once (8 x b128), cache in regs ----
        float4 xc[8];
        float sa[4][NH];
        #pragma unroll
        for (int tok = 0; tok < 4; ++tok)
            #pragma unroll
            for (int hh = 0; hh < NH; ++hh) sa[tok][hh] = 0.f;
        #pragma unroll
        for (int j = 0; j < 8; ++j) {
            float4 xq = lt[(((cseg << 3) + j) << 4) + q];
            xc[j] = xq;
            #pragma unroll
            for (int hh = 0; hh < NH; ++hh) {
                const float uv = u_reg[j][hh];
                sa[0][hh] = fmaf(uv, xq.x, sa[0][hh]);
                sa[1][hh] = fmaf(uv, xq.y, sa[1][hh]);
                sa[2][hh] = fmaf(uv, xq.z, sa[2][hh]);
                sa[3][hh] = fmaf(uv, xq.w, sa[3][hh]);
            }
        }
        // fold the wave's 4 csegs (lane bits 4,5)
        #pragma unroll
        for (int tok = 0; tok < 4; ++tok)
            #pragma unroll
            for (int hh = 0; hh < NH; ++hh) {
                sa[tok][hh] += __shfl_xor(sa[tok][hh], 16);
                sa[tok][hh] += __shfl_xor(sa[tok][hh], 32);
            }
        if (lane < 16) {
            *(float4*)&red_sh[wvid][q][0]  = make_float4(sa[0][0], sa[0][1], sa[0][2], sa[0][3]);
            *(float4*)&red_sh[wvid][q][4]  = make_float4(sa[1][0], sa[1][1], sa[1][2], sa[1][3]);
            *(float4*)&red_sh[wvid][q][8]  = make_float4(sa[2][0], sa[2][1], sa[2][2], sa[2][3]);
            *(float4*)&red_sh[wvid][q][12] = make_float4(sa[3][0], sa[3][1], sa[3][2], sa[3][3]);
        }
        BAR_LGKM();

        // ---- reduce 4 wave-partials -> s; p = exp(s) (no max-shift: |s| << 1) ----
        float s = red_sh[0][t >> 4][th] + red_sh[1][t >> 4][th]
                + red_sh[2][t >> 4][th] + red_sh[3][t >> 4][th];
        float p = __expf(s);
        l_loc += p;
        p_sh[h2][n2] = p;
        BAR_LGKM();

        // ---- ctx from cached tile regs ----
        float4 pq[NH];
        #pragma unroll
        for (int hh = 0; hh < NH; ++hh) pq[hh] = *(const float4*)&p_sh[hh][q << 2];
        #pragma unroll
        for (int j = 0; j < 8; ++j) {
            const float4 xq = xc[j];
            #pragma unroll
            for (int hh = 0; hh < NH; ++hh) {
                float a = acc[hh][j];
                a = fmaf(pq[hh].x, xq.x, a); a = fmaf(pq[hh].y, xq.y, a);
                a = fmaf(pq[hh].z, xq.z, a); a = fmaf(pq[hh].w, xq.w, a);
                acc[hh][j] = a;
            }
        }
        BAR_VM_LGKM();  // prefetch landed; red_sh/p_sh reusable; tile[cur] free
        cur ^= 1;
    }

    // ---- fold acc over the 16 q-lanes (cseg is wave-local, unique per thread-group) ----
    #pragma unroll
    for (int hh = 0; hh < NH; ++hh) {
        #pragma unroll
        for (int j = 0; j < 8; ++j) {
            float v = acc[hh][j];
            v += __shfl_xor(v, 1); v += __shfl_xor(v, 2);
            v += __shfl_xor(v, 4); v += __shfl_xor(v, 8);
            if (q == 0)
                part_ctx[((long)g * NH + hh) * E + (cseg << 3) + j] = v;
        }
    }
    // ---- reduce l: head index is t&3 within wave; fold token bits 2..5 ----
    float r = l_loc;
    r += __shfl_xor(r, 4); r += __shfl_xor(r, 8);
    r += __shfl_xor(r, 16); r += __shfl_xor(r, 32);
    if (lane < 4) lacc[wvid][lane] = r;
    __syncthreads();
    if (t < NH) {
        float L = 0.f;
        #pragma unroll
        for (int w = 0; w < 4; ++w) L += lacc[w][t];
        part_l[g * NH + t] = L;
    }
}

// ---------------- KC: combine partials + V/O projections + LayerNorm (1 block per batch) ----------------
__global__ __launch_bounds__(512)
void kC_combine_outln(const float* __restrict__ part_ctx,
                      const float* __restrict__ part_l,
                      const float* __restrict__ wvw, const float* __restrict__ bv,
                      const float* __restrict__ wo, const float* __restrict__ bo,
                      const float* __restrict__ lng, const float* __restrict__ lnb,
                      float* __restrict__ ln_out)
{
    const int b = blockIdx.x;
    const int t = threadIdx.x;       // 512
    const int lane = t & 63, wv = t >> 6;
    __shared__ float Lsh[8][NH];
    __shared__ float invl_sh[NH];
    __shared__ float sctx[NH][E];
    __shared__ float ctxv[E];
    __shared__ float wbuf[E * PW];
    __shared__ float partred[4][128];
    __shared__ float vec1_sh[128];
    __shared__ float red512[512];

    // phase A: L per head (part_l is B*BPB*NH; 512 threads cover 128 x 4)
    {
        float pl = part_l[(b * BPB + (t >> 2)) * NH + (t & 3)];
        float r = pl;
        r += __shfl_xor(r, 4); r += __shfl_xor(r, 8);
        r += __shfl_xor(r, 16); r += __shfl_xor(r, 32);
        if (lane < 4) Lsh[wv][lane] = r;
    }
    __syncthreads();
    if (t < NH) {
        float L = 0.f;
        #pragma unroll
        for (int w = 0; w < 8; ++w) L += Lsh[w][t];
        invl_sh[t] = 1.f / L;
    }
    __syncthreads();

    // phase B: sctx[h][c] = (sum_i part_ctx[i][h][c]) / L
    {
        const int hB = t >> 7, cB = t & 127;
        const float* pc = part_ctx + (long)b * BPB * NH * E;
        float a0 = 0.f, a1 = 0.f, a2 = 0.f, a3 = 0.f;
        for (int i = 0; i < BPB; i += 4) {
            a0 += pc[((i + 0) * NH + hB) * E + cB];
            a1 += pc[((i + 1) * NH + hB) * E + cB];
            a2 += pc[((i + 2) * NH + hB) * E + cB];
            a3 += pc[((i + 3) * NH + hB) * E + cB];
        }
        sctx[hB][cB] = (a0 + a1 + a2 + a3) * invl_sh[hB];
    }
    __syncthreads();

    // phase C: ctx -> out -> LayerNorm
    for (int i = t; i < E * E; i += 512) wbuf[(i >> 7) * PW + (i & 127)] = wvw[i];
    __syncthreads();
    const int rr = t & 127, qt = t >> 7;
    {
        const int hR = rr >> 5;
        float pa = 0.f;
        #pragma unroll
        for (int c2 = 0; c2 < 32; ++c2)
            pa = fmaf(wbuf[rr * PW + qt * 32 + c2], sctx[hR][qt * 32 + c2], pa);
        partred[qt][rr] = pa;
    }
    __syncthreads();
    if (t < 128)
        vec1_sh[t] = bv[t] + partred[0][t] + partred[1][t] + partred[2][t] + partred[3][t];
    __syncthreads();
    for (int i = t; i < E * E; i += 512) wbuf[(i >> 7) * PW + (i & 127)] = wo[i];
    __syncthreads();
    {
        float po = 0.f;
        #pragma unroll
        for (int c2 = 0; c2 < 32; ++c2)
            po = fmaf(wbuf[rr * PW + qt * 32 + c2], vec1_sh[qt * 32 + c2], po);
        partred[qt][rr] = po;
    }
    __syncthreads();
    float ov = 0.f;
    if (t < 128) ov = bo[t] + partred[0][t] + partred[1][t] + partred[2][t] + partred[3][t];
    red512[t] = (t < 128) ? ov : 0.f;
    __syncthreads();
    for (int st = 64; st > 0; st >>= 1) { if (t < st) red512[t] += red512[t + st]; __syncthreads(); }
    const float mu = red512[0] * (1.f / E);
    __syncthreads();
    const float d = (t < 128) ? (ov - mu) : 0.f;
    red512[t] = d * d;
    __syncthreads();
    for (int st = 64; st > 0; st >>= 1) { if (t < st) red512[t] += red512[t + st]; __syncthreads(); }
    const float var = red512[0] * (1.f / E);
    if (t < 128) ln_out[b * E + t] = d * rsqrtf(var + LN_EPS) * lng[t] + lnb[t];
}

// ---------------- K5: out = x + ln broadcast (streaming, nt stores) ----------------
__global__ void k5_resid(const float* __restrict__ x, const float* __restrict__ ln,
                         float* __restrict__ out, int sh2, long total4)
{
    long i = (long)blockIdx.x * blockDim.x + threadIdx.x;
    const long stride = (long)gridDim.x * blockDim.x;
    for (; i < total4; i += stride) {
        const int bc = (int)(i >> sh2); // b*E + c
        const float l = ln[bc];
        f32x4 v = ((const f32x4*)x)[i];
        v += l;
        __builtin_nontemporal_store(v, ((f32x4*)out) + i);
    }
}

extern "C" void kernel_launch(void* const* d_in, const int* in_sizes, int n_in,
                              void* d_out, int out_size, void* d_ws, size_t ws_size,
                              hipStream_t stream) {
    const float* x   = (const float*)d_in[0];
    const int*   didx= (const int*)d_in[1];
    const float* emb = (const float*)d_in[2];
    const float* qpw = (const float*)d_in[3];
    const float* qpb = (const float*)d_in[4];
    const float* wq  = (const float*)d_in[5];
    const float* bq  = (const float*)d_in[6];
    const float* wk  = (const float*)d_in[7];
    // d_in[8] = bk — cancels in softmax, unused
    const float* wvw = (const float*)d_in[9];
    const float* bv  = (const float*)d_in[10];
    const float* wo  = (const float*)d_in[11];
    const float* bo  = (const float*)d_in[12];
    const float* lng = (const float*)d_in[13];
    const float* lnb = (const float*)d_in[14];
    float* out = (float*)d_out;

    const int B = in_sizes[1];
    const long totalx = (long)in_sizes[0];
    const int N = (int)(totalx / ((long)B * E)); // 131072
    const int nk = N / (CHN * BPB);              // 16 chunks per block
    int lgN = 0; while ((1 << lgN) < N) ++lgN;
    const int sh2 = lgN - 2;

    // workspace layout (floats); all buffers fully written each call
    float* ws       = (float*)d_ws;
    float* u_s      = ws;                                  // B*NH*E
    float* part_l   = u_s      + (long)B * NH * E;         // B*BPB*NH
    float* part_ctx = part_l   + (long)B * BPB * NH;       // B*BPB*NH*E (1 MB @ B=4)
    float* ln_o     = part_ctx + (long)B * BPB * NH * E;   // B*E

    k0_prep<<<1, 512, 0, stream>>>(didx, emb, qpw, qpb, wq, bq, wk, u_s, B);

    kA_attn<<<B * BPB, 256, 0, stream>>>(x, u_s, part_ctx, part_l, N, nk);

    kC_combine_outln<<<B, 512, 0, stream>>>(part_ctx, part_l,
                                            wvw, bv, wo, bo, lng, lnb, ln_o);

    long total4 = (long)B * E * N / 4;
    k5_resid<<<2048, 256, 0, stream>>>(x, ln_o, out, sh2, total4);
}